// Round 3
// baseline (541.415 us; speedup 1.0000x reference)
//
#include <hip/hip_runtime.h>

typedef short short8 __attribute__((ext_vector_type(8)));
typedef float floatx4 __attribute__((ext_vector_type(4)));

#define DI __device__ __forceinline__

constexpr int Bn   = 32;          // batch
constexpr int HW   = 56;          // spatial H == W
constexpr int E    = 384;
constexpr int E3   = 1152;
constexpr int NHd  = 12;
constexpr int HD   = 32;
constexpr int SH   = 4;           // shift
constexpr int T    = 64;          // tokens per window (8x8)
constexpr int NWIN = Bn * 7 * 7;  // 1568 windows
constexpr int MROW = NWIN * T;    // 100352
constexpr int OS   = E3;          // qkv_ws row stride (1152)

DI unsigned short f2bf(float f) {
  unsigned int u = __builtin_bit_cast(unsigned int, f);
  u = u + 0x7FFFu + ((u >> 16) & 1u);   // round-to-nearest-even
  return (unsigned short)(u >> 16);
}

// global -> LDS direct DMA, 16B per lane. LDS dest = wave-uniform base + lane*16
// (m104/m108); global src is per-lane (m173) so the gather + source-side XOR
// swizzle ride on the address computation.
#define GLOAD_LDS16(gsrc, ldst)                                                     \
  __builtin_amdgcn_global_load_lds(                                                 \
      (const __attribute__((address_space(1))) unsigned int*)(gsrc),                \
      (__attribute__((address_space(3))) unsigned int*)(ldst), 16, 0, 0)

// ---------------- kernel 1: x + weights fp32 -> bf16 (one streaming pass) ----------------
__global__ void cast_all(const float* __restrict__ x,
                         const float* __restrict__ wqkv,
                         const float* __restrict__ wout,
                         unsigned short* __restrict__ x_bf,
                         unsigned short* __restrict__ wqkv_bf,
                         unsigned short* __restrict__ wout_bf) {
  const size_t QX = (size_t)Bn * 3136 * E / 4;   // 9,633,792 float4 quads
  const size_t Q1 = QX + (size_t)E3 * E / 4;     // + 110,592
  const size_t Q2 = Q1 + (size_t)E * E / 4;      // + 36,864
  for (size_t i = (size_t)blockIdx.x * 256 + threadIdx.x; i < Q2;
       i += (size_t)gridDim.x * 256) {
    const float* s; unsigned short* d; size_t j;
    if (i < QX)      { s = x;    d = x_bf;    j = i; }
    else if (i < Q1) { s = wqkv; d = wqkv_bf; j = i - QX; }
    else             { s = wout; d = wout_bf; j = i - Q1; }
    const float4 v = *reinterpret_cast<const float4*>(s + j * 4);
    ushort4 h;
    h.x = f2bf(v.x); h.y = f2bf(v.y); h.z = f2bf(v.z); h.w = f2bf(v.w);
    *reinterpret_cast<ushort4*>(d + j * 4) = h;
  }
}

// ---------------- kernel 2: QKV GEMM ----------------
// C[100352 x 1152] = Xw[100352 x 384] @ Wqkv[1152 x 384]^T + b
// 1D grid 7056 = 8 XCDs x 882, XCD-bijective swizzle (T1/m204).
// Staging via global_load_lds width=16 into LINEAR [128][64] LDS tiles.
// Bank-conflict fix is the both-sides involution (rule #21):
//   physical 16B-chunk = logical chunk XOR (row & 7)
// applied to the per-lane GLOBAL source address (stage) and the ds_read
// address (consume). Gives 8 lanes per 4-bank group = b128 minimum.
__global__ __launch_bounds__(256, 2)
void qkv_gemm(const unsigned short* __restrict__ x_bf,     // [B*3136][384] bf16
              const unsigned short* __restrict__ wqkv,     // [1152][384] bf16
              const float* __restrict__ bqkv,              // [1152]
              unsigned short* __restrict__ qkv) {          // [100352][1152] bf16
  __shared__ unsigned short As[128 * 64];   // 16384 B, linear
  __shared__ unsigned short Bs[128 * 64];   // 16384 B, linear

  const int tid  = threadIdx.x;
  const int wave = tid >> 6, lane = tid & 63;
  const int quad = lane >> 4, l16 = lane & 15;
  const int wm = wave >> 1, wn = wave & 1;

  const int orig = blockIdx.x;                 // 7056 = 8 * 882
  const int wgid = (orig & 7) * 882 + (orig >> 3);
  const int m0 = (wgid / 9) * 128, n0 = (wgid % 9) * 128;

  // hoisted per-lane source pointers (constant over kb): f = tid + it*256
  // covers 128 rows x 8 chunks; row = f>>3, phys chunk = f&7,
  // logical chunk = (f&7) ^ (row&7).  A adds the roll+window gather.
  const unsigned short* asrc[4];
  const unsigned short* bsrc[4];
  #pragma unroll
  for (int it = 0; it < 4; ++it) {
    int f = tid + it * 256;              // 0..1023
    int row = f >> 3;
    int clog = (f & 7) ^ (row & 7);
    int m = m0 + row;
    int win = m >> 6, t = m & 63;
    int b = win / 49, wrem = win % 49;
    int wi = wrem / 7, wj = wrem % 7;
    int ti = t >> 3, tj = t & 7;
    int gi = (wi * 8 + ti + SH) % HW;
    int gj = (wj * 8 + tj + SH) % HW;
    asrc[it] = x_bf + (size_t)(b * 3136 + gi * 56 + gj) * E + clog * 8;
    bsrc[it] = wqkv + (size_t)(n0 + row) * E + clog * 8;
  }

  const floatx4 zero4 = {0.f, 0.f, 0.f, 0.f};
  floatx4 acc[4][4];
  #pragma unroll
  for (int mt = 0; mt < 4; ++mt)
    #pragma unroll
    for (int nt = 0; nt < 4; ++nt) acc[mt][nt] = zero4;

  for (int kb = 0; kb < 6; ++kb) {
    // stage: 8 x global_load_lds per thread-iteration group; LDS base is
    // wave-uniform (it*2048 + wave*512 ushorts), lane*16B appended by HW.
    #pragma unroll
    for (int it = 0; it < 4; ++it) {
      GLOAD_LDS16(asrc[it] + kb * 64, As + it * 2048 + wave * 512);
      GLOAD_LDS16(bsrc[it] + kb * 64, Bs + it * 2048 + wave * 512);
    }
    __syncthreads();
    #pragma unroll
    for (int kk = 0; kk < 2; ++kk) {
      short8 af[4], bf[4];
      #pragma unroll
      for (int mt = 0; mt < 4; ++mt)
        af[mt] = *reinterpret_cast<const short8*>(
            &As[(wm * 64 + mt * 16 + l16) * 64 + (((kk * 4 + quad) ^ (l16 & 7)) * 8)]);
      #pragma unroll
      for (int nt = 0; nt < 4; ++nt)
        bf[nt] = *reinterpret_cast<const short8*>(
            &Bs[(wn * 64 + nt * 16 + l16) * 64 + (((kk * 4 + quad) ^ (l16 & 7)) * 8)]);
      #pragma unroll
      for (int mt = 0; mt < 4; ++mt)
        #pragma unroll
        for (int nt = 0; nt < 4; ++nt)
          acc[mt][nt] = __builtin_amdgcn_mfma_f32_16x16x32_bf16(af[mt], bf[nt], acc[mt][nt], 0, 0, 0);
    }
    __syncthreads();
  }

  // epilogue: +bias, bf16, store
  #pragma unroll
  for (int nt = 0; nt < 4; ++nt) {
    int col = n0 + wn * 64 + nt * 16 + l16;
    float bias = bqkv[col];
    #pragma unroll
    for (int mt = 0; mt < 4; ++mt) {
      #pragma unroll
      for (int r = 0; r < 4; ++r) {
        int m = m0 + wm * 64 + mt * 16 + quad * 4 + r;
        qkv[(size_t)m * OS + col] = f2bf(acc[mt][nt][r] + bias);
      }
    }
  }
}

// ---------------- kernel 3: per-(window,head) attention ----------------
// grid = 1568*12 blocks of 64 threads (one wave). O overwrites the q-columns
// of qkv (disjoint per head; all global reads precede writes).
// LDS aliasing: ps (64x72) reuses the q/k region (dead after S=QK^T).
__global__ __launch_bounds__(64)
void attn(unsigned short* __restrict__ qkv) {
  __shared__ unsigned short smem[7424];   // 14848 B
  unsigned short* qs = smem;              // 64 x 40 = 2560
  unsigned short* ks = smem + 2560;       // 64 x 40 = 2560
  unsigned short* ps = smem;              // 64 x 72 = 4608 (aliases qs/ks)
  unsigned short* vT = smem + 5120;       // 32 x 72 = 2304

  const int lane = threadIdx.x;
  const int quad = lane >> 4, l16 = lane & 15;
  const int wh  = blockIdx.x;
  const int win = wh / NHd, h = wh % NHd;
  const size_t base = (size_t)win * T * OS;
  const int hoff = h * HD;

  // ---- stage q, k (64 rows x 32 cols bf16 each) and v^T ----
  #pragma unroll
  for (int it = 0; it < 4; ++it) {
    int c = it * 64 + lane;                // 0..255: 64 rows x 4 short8
    int row = c >> 2, cc = c & 3;
    size_t roff = base + (size_t)row * OS + hoff + cc * 8;
    *reinterpret_cast<short8*>(&qs[row * 40 + cc * 8]) =
        *reinterpret_cast<const short8*>(qkv + roff);
    *reinterpret_cast<short8*>(&ks[row * 40 + cc * 8]) =
        *reinterpret_cast<const short8*>(qkv + roff + E);
  }
  #pragma unroll
  for (int it = 0; it < 4; ++it) {
    int c = it * 64 + lane;
    int t = c >> 2, dc = c & 3;
    short8 vv = *reinterpret_cast<const short8*>(
        qkv + base + (size_t)t * OS + 2 * E + hoff + dc * 8);
    #pragma unroll
    for (int j = 0; j < 8; ++j) vT[(dc * 8 + j) * 72 + t] = (unsigned short)vv[j];
  }
  __syncthreads();

  const floatx4 zero4 = {0.f, 0.f, 0.f, 0.f};

  // ---- S = q k^T (64x64, K=32): 16 MFMAs ----
  short8 aq[4];
  #pragma unroll
  for (int mt = 0; mt < 4; ++mt)
    aq[mt] = *reinterpret_cast<const short8*>(&qs[(mt * 16 + l16) * 40 + quad * 8]);
  floatx4 sacc[4][4];
  #pragma unroll
  for (int nt = 0; nt < 4; ++nt) {
    short8 bk = *reinterpret_cast<const short8*>(&ks[(nt * 16 + l16) * 40 + quad * 8]);
    #pragma unroll
    for (int mt = 0; mt < 4; ++mt)
      sacc[mt][nt] = __builtin_amdgcn_mfma_f32_16x16x32_bf16(aq[mt], bk, zero4, 0, 0, 0);
  }
  __syncthreads();   // q/k LDS dead; ps aliases it

  // ---- row softmax, P -> LDS bf16 ----
  const float scale = 0.17677669529663687f;
  #pragma unroll
  for (int mt = 0; mt < 4; ++mt) {
    #pragma unroll
    for (int r = 0; r < 4; ++r) {
      float s0 = sacc[mt][0][r] * scale, s1 = sacc[mt][1][r] * scale;
      float s2 = sacc[mt][2][r] * scale, s3 = sacc[mt][3][r] * scale;
      float mx = fmaxf(fmaxf(s0, s1), fmaxf(s2, s3));
      #pragma unroll
      for (int off = 1; off < 16; off <<= 1) mx = fmaxf(mx, __shfl_xor(mx, off, 64));
      float e0 = __expf(s0 - mx), e1 = __expf(s1 - mx);
      float e2 = __expf(s2 - mx), e3 = __expf(s3 - mx);
      float sm = e0 + e1 + e2 + e3;
      #pragma unroll
      for (int off = 1; off < 16; off <<= 1) sm += __shfl_xor(sm, off, 64);
      float inv = 1.0f / sm;
      int row = mt * 16 + quad * 4 + r;
      ps[row * 72 +  0 + l16] = f2bf(e0 * inv);
      ps[row * 72 + 16 + l16] = f2bf(e1 * inv);
      ps[row * 72 + 32 + l16] = f2bf(e2 * inv);
      ps[row * 72 + 48 + l16] = f2bf(e3 * inv);
    }
  }
  __syncthreads();

  // ---- O = P V (64x32, K=64): 16 MFMAs; write into q-columns of qkv ----
  #pragma unroll
  for (int mt = 0; mt < 4; ++mt) {
    floatx4 o0 = zero4, o1 = zero4;
    #pragma unroll
    for (int kk = 0; kk < 2; ++kk) {
      short8 ap = *reinterpret_cast<const short8*>(&ps[(mt * 16 + l16) * 72 + kk * 32 + quad * 8]);
      short8 b0 = *reinterpret_cast<const short8*>(&vT[(l16) * 72 + kk * 32 + quad * 8]);
      short8 b1 = *reinterpret_cast<const short8*>(&vT[(16 + l16) * 72 + kk * 32 + quad * 8]);
      o0 = __builtin_amdgcn_mfma_f32_16x16x32_bf16(ap, b0, o0, 0, 0, 0);
      o1 = __builtin_amdgcn_mfma_f32_16x16x32_bf16(ap, b1, o1, 0, 0, 0);
    }
    #pragma unroll
    for (int r = 0; r < 4; ++r) {
      int tok = mt * 16 + quad * 4 + r;
      qkv[base + (size_t)tok * OS + hoff + l16]      = f2bf(o0[r]);
      qkv[base + (size_t)tok * OS + hoff + 16 + l16] = f2bf(o1[r]);
    }
  }
}

// ---------------- kernel 4: out = O @ Wout^T + b, fused window-reverse + roll ----------------
// O lives in qkv's q-columns (row stride 1152, cols 0..383).
// 1D grid 2352 = 8 XCDs x 294, XCD-bijective swizzle; same gload_lds +
// source-XOR staging as qkv_gemm.
__global__ __launch_bounds__(256, 2)
void out_proj(const unsigned short* __restrict__ o_ws,   // [100352][1152] bf16, cols 0..383
              const unsigned short* __restrict__ wout,   // [384][384] bf16
              const float* __restrict__ bout,            // [384]
              float* __restrict__ out) {                 // [32][3136][384] fp32
  __shared__ unsigned short As[128 * 64];
  __shared__ unsigned short Bs[128 * 64];

  const int tid  = threadIdx.x;
  const int wave = tid >> 6, lane = tid & 63;
  const int quad = lane >> 4, l16 = lane & 15;
  const int wm = wave >> 1, wn = wave & 1;

  const int orig = blockIdx.x;                 // 2352 = 8 * 294
  const int wgid = (orig & 7) * 294 + (orig >> 3);
  const int m0 = (wgid / 3) * 128, n0 = (wgid % 3) * 128;

  const unsigned short* asrc[4];
  const unsigned short* bsrc[4];
  #pragma unroll
  for (int it = 0; it < 4; ++it) {
    int f = tid + it * 256;
    int row = f >> 3;
    int clog = (f & 7) ^ (row & 7);
    asrc[it] = o_ws + (size_t)(m0 + row) * OS + clog * 8;
    bsrc[it] = wout + (size_t)(n0 + row) * E + clog * 8;
  }

  const floatx4 zero4 = {0.f, 0.f, 0.f, 0.f};
  floatx4 acc[4][4];
  #pragma unroll
  for (int mt = 0; mt < 4; ++mt)
    #pragma unroll
    for (int nt = 0; nt < 4; ++nt) acc[mt][nt] = zero4;

  for (int kb = 0; kb < 6; ++kb) {
    #pragma unroll
    for (int it = 0; it < 4; ++it) {
      GLOAD_LDS16(asrc[it] + kb * 64, As + it * 2048 + wave * 512);
      GLOAD_LDS16(bsrc[it] + kb * 64, Bs + it * 2048 + wave * 512);
    }
    __syncthreads();
    #pragma unroll
    for (int kk = 0; kk < 2; ++kk) {
      short8 af[4], bf[4];
      #pragma unroll
      for (int mt = 0; mt < 4; ++mt)
        af[mt] = *reinterpret_cast<const short8*>(
            &As[(wm * 64 + mt * 16 + l16) * 64 + (((kk * 4 + quad) ^ (l16 & 7)) * 8)]);
      #pragma unroll
      for (int nt = 0; nt < 4; ++nt)
        bf[nt] = *reinterpret_cast<const short8*>(
            &Bs[(wn * 64 + nt * 16 + l16) * 64 + (((kk * 4 + quad) ^ (l16 & 7)) * 8)]);
      #pragma unroll
      for (int mt = 0; mt < 4; ++mt)
        #pragma unroll
        for (int nt = 0; nt < 4; ++nt)
          acc[mt][nt] = __builtin_amdgcn_mfma_f32_16x16x32_bf16(af[mt], bf[nt], acc[mt][nt], 0, 0, 0);
    }
    __syncthreads();
  }

  #pragma unroll
  for (int nt = 0; nt < 4; ++nt) {
    int col = n0 + wn * 64 + nt * 16 + l16;
    float bias = bout[col];
    #pragma unroll
    for (int mt = 0; mt < 4; ++mt) {
      #pragma unroll
      for (int r = 0; r < 4; ++r) {
        int m = m0 + wm * 64 + mt * 16 + quad * 4 + r;
        int win = m >> 6, t = m & 63;
        int bb = win / 49, wrem = win % 49;
        int wi = wrem / 7, wj = wrem % 7;
        int ti = t >> 3, tj = t & 7;
        int gi = (wi * 8 + ti + SH) % HW;
        int gj = (wj * 8 + tj + SH) % HW;
        out[(size_t)(bb * 3136 + gi * 56 + gj) * E + col] = acc[mt][nt][r] + bias;
      }
    }
  }
}

extern "C" void kernel_launch(void* const* d_in, const int* in_sizes, int n_in,
                              void* d_out, int out_size, void* d_ws, size_t ws_size,
                              hipStream_t stream) {
  (void)in_sizes; (void)n_in; (void)out_size;
  const float* x    = (const float*)d_in[0];
  const float* wqkv = (const float*)d_in[1];
  const float* bqkv = (const float*)d_in[2];
  const float* wout = (const float*)d_in[3];
  const float* bout = (const float*)d_in[4];
  float* out = (float*)d_out;

  unsigned short* wqkv_bf = (unsigned short*)d_ws;                 // 442368 elems
  unsigned short* wout_bf = wqkv_bf + (size_t)E3 * E;              // 147456 elems
  unsigned short* qkv_ws  = wout_bf + (size_t)E * E;               // 100352*1152 elems (~231 MB)

  // x_bf (77 MB): workspace tail if it fits, else d_out as scratch.
  // (x_bf is dead after qkv_gemm; out_proj only WRITES d_out afterwards —
  // no read/write overlap.)
  const size_t xbf_elems = (size_t)Bn * 3136 * E;                  // 38,535,168
  const size_t need_elems = (size_t)E3 * E + (size_t)E * E +
                            (size_t)MROW * E3 + xbf_elems;
  unsigned short* x_bf;
  if (ws_size >= need_elems * sizeof(unsigned short))
    x_bf = qkv_ws + (size_t)MROW * E3;
  else
    x_bf = (unsigned short*)d_out;

  cast_all<<<2048, 256, 0, stream>>>(x, wqkv, wout, x_bf, wqkv_bf, wout_bf);
  qkv_gemm<<<7056, 256, 0, stream>>>(x_bf, wqkv_bf, bqkv, qkv_ws);
  attn<<<NWIN * NHd, 64, 0, stream>>>(qkv_ws);
  out_proj<<<2352, 256, 0, stream>>>(qkv_ws, wout_bf, bout, out);
}

// Round 4
// 519.990 us; speedup vs baseline: 1.0412x; 1.0412x over previous
//
#include <hip/hip_runtime.h>

typedef short short8 __attribute__((ext_vector_type(8)));
typedef float floatx4 __attribute__((ext_vector_type(4)));

#define DI __device__ __forceinline__

constexpr int Bn   = 32;          // batch
constexpr int HW   = 56;          // spatial H == W
constexpr int E    = 384;
constexpr int E3   = 1152;
constexpr int NHd  = 12;
constexpr int HD   = 32;
constexpr int SH   = 4;           // shift
constexpr int T    = 64;          // tokens per window (8x8)
constexpr int NWIN = Bn * 7 * 7;  // 1568 windows
constexpr int MROW = NWIN * T;    // 100352

// head-major qkv layout: [win][head][{q,k,v}][64][32] bf16
// sub-block (win,h,qi) is 64*32 = 2048 elems = 4 KB contiguous.
constexpr int SB   = 2048;        // sub-block elems

DI unsigned short f2bf(float f) {
  unsigned int u = __builtin_bit_cast(unsigned int, f);
  u = u + 0x7FFFu + ((u >> 16) & 1u);   // round-to-nearest-even
  return (unsigned short)(u >> 16);
}

// global -> LDS direct DMA, 16B per lane. LDS dest = wave-uniform base + lane*16
// (m104/m108); global src is per-lane (m173) so gather + source-side XOR
// swizzle ride on the address computation.
#define GLOAD_LDS16(gsrc, ldst)                                                     \
  __builtin_amdgcn_global_load_lds(                                                 \
      (const __attribute__((address_space(1))) unsigned int*)(gsrc),                \
      (__attribute__((address_space(3))) unsigned int*)(ldst), 16, 0, 0)

// ---------------- kernel 1: x + weights fp32 -> bf16 (one streaming pass) ----------------
__global__ void cast_all(const float* __restrict__ x,
                         const float* __restrict__ wqkv,
                         const float* __restrict__ wout,
                         unsigned short* __restrict__ x_bf,
                         unsigned short* __restrict__ wqkv_bf,
                         unsigned short* __restrict__ wout_bf) {
  const size_t QX = (size_t)Bn * 3136 * E / 4;   // 9,633,792 float4 quads
  const size_t Q1 = QX + (size_t)E3 * E / 4;     // + 110,592
  const size_t Q2 = Q1 + (size_t)E * E / 4;      // + 36,864
  for (size_t i = (size_t)blockIdx.x * 256 + threadIdx.x; i < Q2;
       i += (size_t)gridDim.x * 256) {
    const float* s; unsigned short* d; size_t j;
    if (i < QX)      { s = x;    d = x_bf;    j = i; }
    else if (i < Q1) { s = wqkv; d = wqkv_bf; j = i - QX; }
    else             { s = wout; d = wout_bf; j = i - Q1; }
    const float4 v = *reinterpret_cast<const float4*>(s + j * 4);
    ushort4 h;
    h.x = f2bf(v.x); h.y = f2bf(v.y); h.z = f2bf(v.z); h.w = f2bf(v.w);
    *reinterpret_cast<ushort4*>(d + j * 4) = h;
  }
}

// ---------------- kernel 2: QKV GEMM ----------------
// C[100352 x 1152] = Xw[100352 x 384] @ Wqkv[1152 x 384]^T + b
// 1D grid 7056 = 8 XCDs x 882, XCD-bijective swizzle (T1/m204).
// Staging via global_load_lds width=16 into LINEAR [128][64] LDS tiles;
// bank-conflict-free via both-sides XOR involution (phys chunk = logical
// chunk ^ (row&7) on the global SOURCE addr and the ds_read addr).
// Epilogue scatters into the head-major layout (same write cost as before).
__global__ __launch_bounds__(256, 2)
void qkv_gemm(const unsigned short* __restrict__ x_bf,     // [B*3136][384] bf16
              const unsigned short* __restrict__ wqkv,     // [1152][384] bf16
              const float* __restrict__ bqkv,              // [1152]
              unsigned short* __restrict__ qkv) {          // head-major, see SB
  __shared__ unsigned short As[128 * 64];   // 16384 B, linear
  __shared__ unsigned short Bs[128 * 64];   // 16384 B, linear

  const int tid  = threadIdx.x;
  const int wave = tid >> 6, lane = tid & 63;
  const int quad = lane >> 4, l16 = lane & 15;
  const int wm = wave >> 1, wn = wave & 1;

  const int orig = blockIdx.x;                 // 7056 = 8 * 882
  const int wgid = (orig & 7) * 882 + (orig >> 3);
  const int m0 = (wgid / 9) * 128, n0 = (wgid % 9) * 128;

  // hoisted per-lane source pointers (constant over kb): f = tid + it*256
  // covers 128 rows x 8 chunks; row = f>>3, phys chunk = f&7,
  // logical chunk = (f&7) ^ (row&7).  A adds the roll+window gather.
  const unsigned short* asrc[4];
  const unsigned short* bsrc[4];
  #pragma unroll
  for (int it = 0; it < 4; ++it) {
    int f = tid + it * 256;              // 0..1023
    int row = f >> 3;
    int clog = (f & 7) ^ (row & 7);
    int m = m0 + row;
    int win = m >> 6, t = m & 63;
    int b = win / 49, wrem = win % 49;
    int wi = wrem / 7, wj = wrem % 7;
    int ti = t >> 3, tj = t & 7;
    int gi = (wi * 8 + ti + SH) % HW;
    int gj = (wj * 8 + tj + SH) % HW;
    asrc[it] = x_bf + (size_t)(b * 3136 + gi * 56 + gj) * E + clog * 8;
    bsrc[it] = wqkv + (size_t)(n0 + row) * E + clog * 8;
  }

  const floatx4 zero4 = {0.f, 0.f, 0.f, 0.f};
  floatx4 acc[4][4];
  #pragma unroll
  for (int mt = 0; mt < 4; ++mt)
    #pragma unroll
    for (int nt = 0; nt < 4; ++nt) acc[mt][nt] = zero4;

  for (int kb = 0; kb < 6; ++kb) {
    #pragma unroll
    for (int it = 0; it < 4; ++it) {
      GLOAD_LDS16(asrc[it] + kb * 64, As + it * 2048 + wave * 512);
      GLOAD_LDS16(bsrc[it] + kb * 64, Bs + it * 2048 + wave * 512);
    }
    __syncthreads();
    #pragma unroll
    for (int kk = 0; kk < 2; ++kk) {
      short8 af[4], bf[4];
      #pragma unroll
      for (int mt = 0; mt < 4; ++mt)
        af[mt] = *reinterpret_cast<const short8*>(
            &As[(wm * 64 + mt * 16 + l16) * 64 + (((kk * 4 + quad) ^ (l16 & 7)) * 8)]);
      #pragma unroll
      for (int nt = 0; nt < 4; ++nt)
        bf[nt] = *reinterpret_cast<const short8*>(
            &Bs[(wn * 64 + nt * 16 + l16) * 64 + (((kk * 4 + quad) ^ (l16 & 7)) * 8)]);
      #pragma unroll
      for (int mt = 0; mt < 4; ++mt)
        #pragma unroll
        for (int nt = 0; nt < 4; ++nt)
          acc[mt][nt] = __builtin_amdgcn_mfma_f32_16x16x32_bf16(af[mt], bf[nt], acc[mt][nt], 0, 0, 0);
    }
    __syncthreads();
  }

  // epilogue: +bias, bf16, scatter into head-major layout
  #pragma unroll
  for (int nt = 0; nt < 4; ++nt) {
    int col = n0 + wn * 64 + nt * 16 + l16;
    float bias = bqkv[col];
    int qi = col / 384;
    int hcol = col - qi * 384;
    int hh = hcol >> 5, d = hcol & 31;
    #pragma unroll
    for (int mt = 0; mt < 4; ++mt) {
      #pragma unroll
      for (int r = 0; r < 4; ++r) {
        int m = m0 + wm * 64 + mt * 16 + quad * 4 + r;
        int win = m >> 6, t = m & 63;
        qkv[((size_t)(win * NHd + hh) * 3 + qi) * SB + t * 32 + d] =
            f2bf(acc[mt][nt][r] + bias);
      }
    }
  }
}

// ---------------- kernel 3: per-(window,head) attention ----------------
// grid = 1568*12 blocks of 64 threads (one wave). Head-major layout makes the
// block's q,k,v one contiguous 12 KB region: q/k fragments load straight from
// global to registers (coalesced 1 KB/instr); only v^T and P use LDS.
// O overwrites the q sub-block (reads precede writes within the block).
__global__ __launch_bounds__(64)
void attn(unsigned short* __restrict__ qkv) {
  __shared__ unsigned short smem[6912];   // 13824 B
  unsigned short* ps = smem;              // 64 x 72 = 4608
  unsigned short* vT = smem + 4608;       // 32 x 72 = 2304

  const int lane = threadIdx.x;
  const int quad = lane >> 4, l16 = lane & 15;
  const int wh  = blockIdx.x;
  const int win = wh / NHd, h = wh % NHd;
  const size_t bq = (size_t)(win * NHd + h) * 3 * SB;   // q sub-block

  // ---- stage v^T (v is 64x32 contiguous at bq + 2*SB) ----
  #pragma unroll
  for (int it = 0; it < 4; ++it) {
    int c = it * 64 + lane;                       // 0..255 short8 chunks
    int t = c >> 2, dc = c & 3;
    short8 vv = *reinterpret_cast<const short8*>(qkv + bq + 2 * SB + c * 8);
    #pragma unroll
    for (int j = 0; j < 8; ++j) vT[(dc * 8 + j) * 72 + t] = (unsigned short)vv[j];
  }

  // ---- q,k fragments direct from global (each load: 64 lanes x 16 B = 1 KB) ----
  short8 aq[4], bk[4];
  #pragma unroll
  for (int mt = 0; mt < 4; ++mt)
    aq[mt] = *reinterpret_cast<const short8*>(
        qkv + bq + (size_t)(mt * 16 + l16) * 32 + quad * 8);
  #pragma unroll
  for (int nt = 0; nt < 4; ++nt)
    bk[nt] = *reinterpret_cast<const short8*>(
        qkv + bq + SB + (size_t)(nt * 16 + l16) * 32 + quad * 8);

  const floatx4 zero4 = {0.f, 0.f, 0.f, 0.f};

  // ---- S = q k^T (64x64, K=32): 16 MFMAs ----
  floatx4 sacc[4][4];
  #pragma unroll
  for (int nt = 0; nt < 4; ++nt)
    #pragma unroll
    for (int mt = 0; mt < 4; ++mt)
      sacc[mt][nt] = __builtin_amdgcn_mfma_f32_16x16x32_bf16(aq[mt], bk[nt], zero4, 0, 0, 0);

  // ---- row softmax, P -> LDS bf16 ----
  const float scale = 0.17677669529663687f;
  #pragma unroll
  for (int mt = 0; mt < 4; ++mt) {
    #pragma unroll
    for (int r = 0; r < 4; ++r) {
      float s0 = sacc[mt][0][r] * scale, s1 = sacc[mt][1][r] * scale;
      float s2 = sacc[mt][2][r] * scale, s3 = sacc[mt][3][r] * scale;
      float mx = fmaxf(fmaxf(s0, s1), fmaxf(s2, s3));
      #pragma unroll
      for (int off = 1; off < 16; off <<= 1) mx = fmaxf(mx, __shfl_xor(mx, off, 64));
      float e0 = __expf(s0 - mx), e1 = __expf(s1 - mx);
      float e2 = __expf(s2 - mx), e3 = __expf(s3 - mx);
      float sm = e0 + e1 + e2 + e3;
      #pragma unroll
      for (int off = 1; off < 16; off <<= 1) sm += __shfl_xor(sm, off, 64);
      float inv = 1.0f / sm;
      int row = mt * 16 + quad * 4 + r;
      ps[row * 72 +  0 + l16] = f2bf(e0 * inv);
      ps[row * 72 + 16 + l16] = f2bf(e1 * inv);
      ps[row * 72 + 32 + l16] = f2bf(e2 * inv);
      ps[row * 72 + 48 + l16] = f2bf(e3 * inv);
    }
  }
  __syncthreads();   // vT + ps visible before PV

  // ---- O = P V (64x32, K=64): 16 MFMAs; write into q sub-block ----
  #pragma unroll
  for (int mt = 0; mt < 4; ++mt) {
    floatx4 o0 = zero4, o1 = zero4;
    #pragma unroll
    for (int kk = 0; kk < 2; ++kk) {
      short8 ap = *reinterpret_cast<const short8*>(&ps[(mt * 16 + l16) * 72 + kk * 32 + quad * 8]);
      short8 b0 = *reinterpret_cast<const short8*>(&vT[(l16) * 72 + kk * 32 + quad * 8]);
      short8 b1 = *reinterpret_cast<const short8*>(&vT[(16 + l16) * 72 + kk * 32 + quad * 8]);
      o0 = __builtin_amdgcn_mfma_f32_16x16x32_bf16(ap, b0, o0, 0, 0, 0);
      o1 = __builtin_amdgcn_mfma_f32_16x16x32_bf16(ap, b1, o1, 0, 0, 0);
    }
    #pragma unroll
    for (int r = 0; r < 4; ++r) {
      int tok = mt * 16 + quad * 4 + r;
      qkv[bq + tok * 32 + l16]      = f2bf(o0[r]);
      qkv[bq + tok * 32 + 16 + l16] = f2bf(o1[r]);
    }
  }
}

// ---------------- kernel 4: out = O @ Wout^T + b, fused window-reverse + roll ----------------
// O lives in the q sub-blocks of the head-major layout: logical A element
// (m, k) = qkv[((win*12 + (k>>5))*3)*SB + t*32 + (k&31)] — contiguous 4 KB
// per (win,head), kb advances h by 2 (+12288 elems, linear).
// 1D grid 2352 = 8 XCDs x 294, XCD-bijective swizzle; gload_lds + XOR staging.
__global__ __launch_bounds__(256, 2)
void out_proj(const unsigned short* __restrict__ o_ws,   // head-major qkv base
              const unsigned short* __restrict__ wout,   // [384][384] bf16
              const float* __restrict__ bout,            // [384]
              float* __restrict__ out) {                 // [32][3136][384] fp32
  __shared__ unsigned short As[128 * 64];
  __shared__ unsigned short Bs[128 * 64];

  const int tid  = threadIdx.x;
  const int wave = tid >> 6, lane = tid & 63;
  const int quad = lane >> 4, l16 = lane & 15;
  const int wm = wave >> 1, wn = wave & 1;

  const int orig = blockIdx.x;                 // 2352 = 8 * 294
  const int wgid = (orig & 7) * 294 + (orig >> 3);
  const int m0 = (wgid / 3) * 128, n0 = (wgid % 3) * 128;

  const unsigned short* asrc[4];
  const unsigned short* bsrc[4];
  #pragma unroll
  for (int it = 0; it < 4; ++it) {
    int f = tid + it * 256;
    int row = f >> 3;
    int clog = (f & 7) ^ (row & 7);
    int m = m0 + row;
    int win = m >> 6, t = m & 63;
    int h0 = clog >> 2, d0 = (clog & 3) * 8;
    asrc[it] = o_ws + (size_t)(win * NHd + h0) * 3 * SB + t * 32 + d0;
    bsrc[it] = wout + (size_t)(n0 + row) * E + clog * 8;
  }

  const floatx4 zero4 = {0.f, 0.f, 0.f, 0.f};
  floatx4 acc[4][4];
  #pragma unroll
  for (int mt = 0; mt < 4; ++mt)
    #pragma unroll
    for (int nt = 0; nt < 4; ++nt) acc[mt][nt] = zero4;

  for (int kb = 0; kb < 6; ++kb) {
    #pragma unroll
    for (int it = 0; it < 4; ++it) {
      GLOAD_LDS16(asrc[it] + kb * (2 * 3 * SB), As + it * 2048 + wave * 512);
      GLOAD_LDS16(bsrc[it] + kb * 64, Bs + it * 2048 + wave * 512);
    }
    __syncthreads();
    #pragma unroll
    for (int kk = 0; kk < 2; ++kk) {
      short8 af[4], bf[4];
      #pragma unroll
      for (int mt = 0; mt < 4; ++mt)
        af[mt] = *reinterpret_cast<const short8*>(
            &As[(wm * 64 + mt * 16 + l16) * 64 + (((kk * 4 + quad) ^ (l16 & 7)) * 8)]);
      #pragma unroll
      for (int nt = 0; nt < 4; ++nt)
        bf[nt] = *reinterpret_cast<const short8*>(
            &Bs[(wn * 64 + nt * 16 + l16) * 64 + (((kk * 4 + quad) ^ (l16 & 7)) * 8)]);
      #pragma unroll
      for (int mt = 0; mt < 4; ++mt)
        #pragma unroll
        for (int nt = 0; nt < 4; ++nt)
          acc[mt][nt] = __builtin_amdgcn_mfma_f32_16x16x32_bf16(af[mt], bf[nt], acc[mt][nt], 0, 0, 0);
    }
    __syncthreads();
  }

  #pragma unroll
  for (int nt = 0; nt < 4; ++nt) {
    int col = n0 + wn * 64 + nt * 16 + l16;
    float bias = bout[col];
    #pragma unroll
    for (int mt = 0; mt < 4; ++mt) {
      #pragma unroll
      for (int r = 0; r < 4; ++r) {
        int m = m0 + wm * 64 + mt * 16 + quad * 4 + r;
        int win = m >> 6, t = m & 63;
        int bb = win / 49, wrem = win % 49;
        int wi = wrem / 7, wj = wrem % 7;
        int ti = t >> 3, tj = t & 7;
        int gi = (wi * 8 + ti + SH) % HW;
        int gj = (wj * 8 + tj + SH) % HW;
        out[(size_t)(bb * 3136 + gi * 56 + gj) * E + col] = acc[mt][nt][r] + bias;
      }
    }
  }
}

extern "C" void kernel_launch(void* const* d_in, const int* in_sizes, int n_in,
                              void* d_out, int out_size, void* d_ws, size_t ws_size,
                              hipStream_t stream) {
  (void)in_sizes; (void)n_in; (void)out_size;
  const float* x    = (const float*)d_in[0];
  const float* wqkv = (const float*)d_in[1];
  const float* bqkv = (const float*)d_in[2];
  const float* wout = (const float*)d_in[3];
  const float* bout = (const float*)d_in[4];
  float* out = (float*)d_out;

  unsigned short* wqkv_bf = (unsigned short*)d_ws;                 // 442368 elems
  unsigned short* wout_bf = wqkv_bf + (size_t)E3 * E;              // 147456 elems
  unsigned short* qkv_ws  = wout_bf + (size_t)E * E;               // 100352*1152 elems (~231 MB)

  // x_bf (77 MB): workspace tail if it fits, else d_out as scratch.
  // (x_bf is dead after qkv_gemm; attn/out_proj never touch it; out_proj only
  // WRITES d_out afterwards — no read/write overlap.)
  const size_t xbf_elems = (size_t)Bn * 3136 * E;                  // 38,535,168
  const size_t need_elems = (size_t)E3 * E + (size_t)E * E +
                            (size_t)MROW * E3 + xbf_elems;
  unsigned short* x_bf;
  if (ws_size >= need_elems * sizeof(unsigned short))
    x_bf = qkv_ws + (size_t)MROW * E3;
  else
    x_bf = (unsigned short*)d_out;

  cast_all<<<2048, 256, 0, stream>>>(x, wqkv, wout, x_bf, wqkv_bf, wout_bf);
  qkv_gemm<<<7056, 256, 0, stream>>>(x_bf, wqkv_bf, bqkv, qkv_ws);
  attn<<<NWIN * NHd, 64, 0, stream>>>(qkv_ws);
  out_proj<<<2352, 256, 0, stream>>>(qkv_ws, wout_bf, bout, out);
}